// Round 1
// 375.236 us; speedup vs baseline: 1.0040x; 1.0040x over previous
//
#include <hip/hip_runtime.h>

#define NPTS 1024
#define NC 256
#define NH 360
#define NW 360
#define NHW (NH * NW)
#define NCHW (NC * NHW)
#define PPB 4       // points per MLP block (was 8) -> 512 blocks = 2 blocks/CU
#define PAD 5       // LDS row stride for [c][p] activation tiles (stride 5 -> conflict-free-ish)

// ---------------------------------------------------------------------------
// Kernel 1: fused gather + register-tiled 3-layer MLP.
// 4 points/block, 256 threads, 512 blocks (2 blocks/CU: one block's compute
// overlaps the other block's scattered-gather latency).
// Gather goes straight into the transposed LDS tile (no X round-trip).
// Writes pq[2048][32]: rows 0..1023 = f1 @ w3, rows 1024..2047 = b3 - f2 @ w3.
// ---------------------------------------------------------------------------
__global__ __launch_bounds__(256) void mlp_kernel(
    const float* __restrict__ feature,
    const int* __restrict__ idx1,
    const int* __restrict__ idx2,
    const float* __restrict__ w1, const float* __restrict__ b1,
    const float* __restrict__ w2, const float* __restrict__ b2,
    const float* __restrict__ w3, const float* __restrict__ b3,
    float* __restrict__ pq)
{
    __shared__ float Xs[256 * PAD];   // [c][p], 5 KB
    __shared__ float H1s[256 * PAD];  // [j][p], 5 KB
    __shared__ float F2s[128 * PAD];  // [j][p], 2.5 KB

    const int tid = threadIdx.x;      // 0..255
    const int base = blockIdx.x * PPB;

    // ---- fused gather: Xs[c][p] = feature[b_p, c, h_p, w_p] ----
    // 256 threads x 4 points each; idx rows are block-uniform -> s_load_dwordx4.
    {
        const int c = tid;
        const int col0 = base & (NPTS - 1);              // multiple of 4
        const int* idx = (base < NPTS) ? idx1 : idx2;    // uniform per block
        const int4 bb4 = *(const int4*)(idx + col0);
        const int4 hh4 = *(const int4*)(idx + NPTS + col0);
        const int4 ww4 = *(const int4*)(idx + 2 * NPTS + col0);
        const size_t coff = (size_t)c * NHW;             // per-lane offset, shared by all 4 loads
        // 4 independent scattered loads, all in flight together
        float v0 = feature[(size_t)bb4.x * NCHW + coff + (size_t)(hh4.x * NW + ww4.x)];
        float v1 = feature[(size_t)bb4.y * NCHW + coff + (size_t)(hh4.y * NW + ww4.y)];
        float v2 = feature[(size_t)bb4.z * NCHW + coff + (size_t)(hh4.z * NW + ww4.z)];
        float v3 = feature[(size_t)bb4.w * NCHW + coff + (size_t)(ww4.w + hh4.w * NW)];
        Xs[c * PAD + 0] = v0;
        Xs[c * PAD + 1] = v1;
        Xs[c * PAD + 2] = v2;
        Xs[c * PAD + 3] = v3;
    }
    __syncthreads();

    const int jt = tid & 63;          // weight-vector lane
    const int pt = tid >> 6;          // 0..3 -> point

    // ---- layer 1: 256 -> 256, each thread: 1 point x 4 outputs ----
    {
        const float4* w1v = (const float4*)w1;    // w1v[c*64 + jt]
        float acc[4] = {0.f, 0.f, 0.f, 0.f};
        #pragma unroll 8
        for (int c = 0; c < 256; ++c) {
            float4 wv = w1v[c * 64 + jt];
            float a = Xs[c * PAD + pt];           // wave-uniform -> LDS broadcast
            acc[0] = fmaf(a, wv.x, acc[0]);
            acc[1] = fmaf(a, wv.y, acc[1]);
            acc[2] = fmaf(a, wv.z, acc[2]);
            acc[3] = fmaf(a, wv.w, acc[3]);
        }
        const int j0 = jt * 4;
        #pragma unroll
        for (int q = 0; q < 4; ++q)
            H1s[(j0 + q) * PAD + pt] = fmaxf(acc[q] + b1[j0 + q], 0.f);
    }
    __syncthreads();

    // ---- layer 2: 256 -> 128, each thread: 1 point x 2 outputs ----
    {
        const float2* w2v = (const float2*)w2;    // w2v[c*64 + jt]
        float acc[2] = {0.f, 0.f};
        #pragma unroll 8
        for (int c = 0; c < 256; ++c) {
            float2 wv = w2v[c * 64 + jt];
            float a = H1s[c * PAD + pt];
            acc[0] = fmaf(a, wv.x, acc[0]);
            acc[1] = fmaf(a, wv.y, acc[1]);
        }
        const int j0 = jt * 2;
        F2s[(j0 + 0) * PAD + pt] = fmaxf(acc[0] + b2[j0 + 0], 0.f);
        F2s[(j0 + 1) * PAD + pt] = fmaxf(acc[1] + b2[j0 + 1], 0.f);
    }
    __syncthreads();

    // ---- layer 3 (no relu): pq[g][j] = sum_c F2[g][c]*w3[c][j] ----
    if (tid < 128) {
        const int j = tid & 31;
        const int g = tid >> 5;       // 0..3
        float acc = 0.f;
        #pragma unroll 8
        for (int c = 0; c < 128; ++c)
            acc = fmaf(F2s[c * PAD + g], w3[c * 32 + j], acc);
        const int point = base + g;
        float val = (point < NPTS) ? acc : (b3[j] - acc);
        pq[(size_t)point * 32 + j] = val;   // coalesced
    }
}

// ---------------------------------------------------------------------------
// Kernel 2: out[m][n] = b4 + sum_k w4[k] * relu(p1[m][k] + q2[n][k])
// Grid: (4 n-tiles, 128 m-tiles) = 512 blocks, 256 threads (one n, 8 m's).
// P-rows and w4 are block-uniform -> scalar (SGPR) loads; q in VGPRs.
// Inner loop is 3 VALU ops / element, zero LDS, no barriers.
// ---------------------------------------------------------------------------
#define MT 8

__global__ __launch_bounds__(256) void pair_kernel(
    const float* __restrict__ pq,
    const float* __restrict__ w4,
    const float* __restrict__ b4,
    float* __restrict__ out)
{
    const int tid = threadIdx.x;
    const int n = blockIdx.x * 256 + tid;
    const int m0 = blockIdx.y * MT;

    // q[n][0..31] in registers via 8x dwordx4
    float q[32];
    const float4* q4 = (const float4*)(pq + (size_t)(NPTS + n) * 32);
    #pragma unroll
    for (int k8 = 0; k8 < 8; ++k8) {
        float4 t = q4[k8];
        q[4 * k8 + 0] = t.x;
        q[4 * k8 + 1] = t.y;
        q[4 * k8 + 2] = t.z;
        q[4 * k8 + 3] = t.w;
    }
    const float b4v = b4[0];          // uniform -> SGPR

    #pragma unroll
    for (int mm = 0; mm < MT; ++mm) {
        const float* Pm = pq + (size_t)(m0 + mm) * 32;   // uniform row -> s_load
        float a = b4v;
        #pragma unroll
        for (int k = 0; k < 32; ++k) {
            float t = Pm[k] + q[k];                      // v_add (sgpr + vgpr)
            a = fmaf(w4[k], fmaxf(t, 0.f), a);           // v_max, v_fma (sgpr mul)
        }
        out[(size_t)(m0 + mm) * 1024 + n] = a;           // coalesced over n
    }
}

extern "C" void kernel_launch(void* const* d_in, const int* in_sizes, int n_in,
                              void* d_out, int out_size, void* d_ws, size_t ws_size,
                              hipStream_t stream) {
    const float* feature = (const float*)d_in[0];
    const int*   idx1    = (const int*)d_in[1];
    const int*   idx2    = (const int*)d_in[2];
    const float* w1      = (const float*)d_in[3];
    const float* b1      = (const float*)d_in[4];
    const float* w2      = (const float*)d_in[5];
    const float* b2      = (const float*)d_in[6];
    const float* w3      = (const float*)d_in[7];
    const float* b3      = (const float*)d_in[8];
    const float* w4      = (const float*)d_in[9];
    const float* b4      = (const float*)d_in[10];
    float* out = (float*)d_out;

    float* pq = (float*)d_ws;                       // 2048*32*4 = 256 KB

    mlp_kernel<<<2048 / PPB, 256, 0, stream>>>(
        feature, idx1, idx2, w1, b1, w2, b2, w3, b3, pq);

    pair_kernel<<<dim3(4, 128), 256, 0, stream>>>(pq, w4, b4, out);
}

// Round 2
// 360.736 us; speedup vs baseline: 1.0443x; 1.0402x over previous
//
#include <hip/hip_runtime.h>

#define NPTS 1024
#define NC 256
#define NH 360
#define NW 360
#define NHW (NH * NW)
#define NCHW (NC * NHW)
#define PPB 4       // points per MLP block -> 512 blocks = 2 blocks/CU

// ---------------------------------------------------------------------------
// Kernel 1: fused gather + 3-layer MLP, thread->output-column mapping.
// 4 points/block, 256 threads, 512 blocks (2 blocks/CU for gather/compute
// overlap). Each thread owns ONE output column for ALL 4 points:
//  - weights are read as per-thread scalars (coalesced, w1 read 1x/block,
//    w2 2x/block -> L2 weight traffic 786 MB -> 262 MB vs previous mapping)
//  - activations are float4 [c] -> one ds_read_b128 broadcast per c
// Writes pq[2048][32]: rows 0..1023 = f1 @ w3, rows 1024..2047 = b3 - f2 @ w3.
// ---------------------------------------------------------------------------
__global__ __launch_bounds__(256) void mlp_kernel(
    const float* __restrict__ feature,
    const int* __restrict__ idx1,
    const int* __restrict__ idx2,
    const float* __restrict__ w1, const float* __restrict__ b1,
    const float* __restrict__ w2, const float* __restrict__ b2,
    const float* __restrict__ w3, const float* __restrict__ b3,
    float* __restrict__ pq)
{
    __shared__ float4 Xs[256];    // [c] -> 4 points, 4 KB
    __shared__ float4 H1s[256];   // [j] -> 4 points, 4 KB
    __shared__ float4 F2s[128];   // [j] -> 4 points, 2 KB

    const int tid = threadIdx.x;      // 0..255
    const int base = blockIdx.x * PPB;

    // ---- fused gather: Xs[c] = feature[b_p, c, h_p, w_p] for p=0..3 ----
    // 256 threads (one channel each) x 4 points; idx rows block-uniform.
    // Non-temporal: 33-67 MB of scattered lines have zero reuse -> don't
    // evict the hot 384 KB weight set from L2.
    {
        const int c = tid;
        const int col0 = base & (NPTS - 1);              // multiple of 4
        const int* idx = (base < NPTS) ? idx1 : idx2;    // uniform per block
        const int4 bb4 = *(const int4*)(idx + col0);
        const int4 hh4 = *(const int4*)(idx + NPTS + col0);
        const int4 ww4 = *(const int4*)(idx + 2 * NPTS + col0);
        const size_t coff = (size_t)c * NHW;
        float4 v;
        v.x = __builtin_nontemporal_load(
                  feature + (size_t)bb4.x * NCHW + coff + (size_t)(hh4.x * NW + ww4.x));
        v.y = __builtin_nontemporal_load(
                  feature + (size_t)bb4.y * NCHW + coff + (size_t)(hh4.y * NW + ww4.y));
        v.z = __builtin_nontemporal_load(
                  feature + (size_t)bb4.z * NCHW + coff + (size_t)(hh4.z * NW + ww4.z));
        v.w = __builtin_nontemporal_load(
                  feature + (size_t)bb4.w * NCHW + coff + (size_t)(hh4.w * NW + ww4.w));
        Xs[c] = v;                                       // b128 write
    }
    __syncthreads();

    // ---- layer 1: 256 -> 256. thread t -> column j=t, 4 points ----
    {
        const int j = tid;
        float4 acc = make_float4(0.f, 0.f, 0.f, 0.f);
        #pragma unroll 8
        for (int c = 0; c < 256; ++c) {
            const float wv = w1[c * 256 + j];   // scalar, coalesced per wave
            const float4 a = Xs[c];             // ds_read_b128 broadcast
            acc.x = fmaf(a.x, wv, acc.x);
            acc.y = fmaf(a.y, wv, acc.y);
            acc.z = fmaf(a.z, wv, acc.z);
            acc.w = fmaf(a.w, wv, acc.w);
        }
        const float bj = b1[j];
        float4 h;
        h.x = fmaxf(acc.x + bj, 0.f);
        h.y = fmaxf(acc.y + bj, 0.f);
        h.z = fmaxf(acc.z + bj, 0.f);
        h.w = fmaxf(acc.w + bj, 0.f);
        H1s[j] = h;
    }
    __syncthreads();

    // ---- layer 2: 256 -> 128. thread t -> column j=t&127, point-pair t>>7 ----
    {
        const int j = tid & 127;
        const int ph = tid >> 7;                // wave-uniform (waves 0,1 vs 2,3)
        const float* H1f = (const float*)H1s;
        float2 acc = make_float2(0.f, 0.f);
        #pragma unroll 8
        for (int c = 0; c < 256; ++c) {
            const float wv = w2[c * 128 + j];   // scalar, coalesced
            const float2 a = *(const float2*)&H1f[c * 4 + 2 * ph];  // b64 broadcast
            acc.x = fmaf(a.x, wv, acc.x);
            acc.y = fmaf(a.y, wv, acc.y);
        }
        const float bj = b2[j];
        float* F2f = (float*)F2s;
        F2f[j * 4 + 2 * ph + 0] = fmaxf(acc.x + bj, 0.f);
        F2f[j * 4 + 2 * ph + 1] = fmaxf(acc.y + bj, 0.f);
    }
    __syncthreads();

    // ---- layer 3 (no relu): pq[g][j] = sum_c F2[g][c]*w3[c][j] ----
    if (tid < 128) {
        const int j = tid & 31;
        const int g = tid >> 5;       // 0..3
        const float* F2f = (const float*)F2s;
        float acc = 0.f;
        #pragma unroll 8
        for (int c = 0; c < 128; ++c)
            acc = fmaf(F2f[c * 4 + g], w3[c * 32 + j], acc);
        const int point = base + g;
        const float val = (point < NPTS) ? acc : (b3[j] - acc);
        pq[(size_t)point * 32 + j] = val;   // coalesced
    }
}

// ---------------------------------------------------------------------------
// Kernel 2: out[m][n] = b4 + sum_k w4[k] * relu(p1[m][k] + q2[n][k])
// Grid: (4 n-tiles, 128 m-tiles) = 512 blocks, 256 threads (one n, 8 m's).
// P-rows and w4 are block-uniform -> scalar (SGPR) loads; q in VGPRs.
// Inner loop is 3 VALU ops / element, zero LDS, no barriers.
// ---------------------------------------------------------------------------
#define MT 8

__global__ __launch_bounds__(256) void pair_kernel(
    const float* __restrict__ pq,
    const float* __restrict__ w4,
    const float* __restrict__ b4,
    float* __restrict__ out)
{
    const int tid = threadIdx.x;
    const int n = blockIdx.x * 256 + tid;
    const int m0 = blockIdx.y * MT;

    // q[n][0..31] in registers via 8x dwordx4
    float q[32];
    const float4* q4 = (const float4*)(pq + (size_t)(NPTS + n) * 32);
    #pragma unroll
    for (int k8 = 0; k8 < 8; ++k8) {
        float4 t = q4[k8];
        q[4 * k8 + 0] = t.x;
        q[4 * k8 + 1] = t.y;
        q[4 * k8 + 2] = t.z;
        q[4 * k8 + 3] = t.w;
    }
    const float b4v = b4[0];          // uniform -> SGPR

    #pragma unroll
    for (int mm = 0; mm < MT; ++mm) {
        const float* Pm = pq + (size_t)(m0 + mm) * 32;   // uniform row -> s_load
        float a = b4v;
        #pragma unroll
        for (int k = 0; k < 32; ++k) {
            float t = Pm[k] + q[k];                      // v_add (sgpr + vgpr)
            a = fmaf(w4[k], fmaxf(t, 0.f), a);           // v_max, v_fma (sgpr mul)
        }
        out[(size_t)(m0 + mm) * 1024 + n] = a;           // coalesced over n
    }
}

extern "C" void kernel_launch(void* const* d_in, const int* in_sizes, int n_in,
                              void* d_out, int out_size, void* d_ws, size_t ws_size,
                              hipStream_t stream) {
    const float* feature = (const float*)d_in[0];
    const int*   idx1    = (const int*)d_in[1];
    const int*   idx2    = (const int*)d_in[2];
    const float* w1      = (const float*)d_in[3];
    const float* b1      = (const float*)d_in[4];
    const float* w2      = (const float*)d_in[5];
    const float* b2      = (const float*)d_in[6];
    const float* w3      = (const float*)d_in[7];
    const float* b3      = (const float*)d_in[8];
    const float* w4      = (const float*)d_in[9];
    const float* b4      = (const float*)d_in[10];
    float* out = (float*)d_out;

    float* pq = (float*)d_ws;                       // 2048*32*4 = 256 KB

    mlp_kernel<<<2048 / PPB, 256, 0, stream>>>(
        feature, idx1, idx2, w1, b1, w2, b2, w3, b3, pq);

    pair_kernel<<<dim3(4, 128), 256, 0, stream>>>(pq, w4, b4, out);
}